// Round 4
// baseline (106.665 us; speedup 1.0000x reference)
//
#include <hip/hip_runtime.h>
#include <hip/hip_fp16.h>
#include <math.h>

// SSIM loss, fused single-pass.
// Stage AB: h-blur of {x, y, x^2+y^2, xy} read directly from global (L1) -> LDS (fp16).
// Stage C : v-blur + SSIM map + reduction.
// fp16 LDS planes: 22.8 KB/block -> 7 blocks/CU (87% occupancy).
// Input: image, target fp32 [16,3,512,512]. Output: 1 scalar fp32.

#define HH 512
#define WW 512
#define NPLANES 48
#define TW 64                 // output tile width
#define TH 32                 // output tile height
#define RAD 5
#define IH (TH + 2*RAD)       // 42 staged rows
#define HBS4 17               // hb row stride in half4 units (68 halves; 34 words, %32=2)
#define KW 11

typedef __attribute__((ext_vector_type(4))) _Float16 h4;

struct GaussW { float g[KW]; };

__global__ void ssim_init_out(float* out) { out[0] = 1.0f; }

__global__ __launch_bounds__(256, 7)
void ssim_fused(const float* __restrict__ img, const float* __restrict__ tgt,
                float* __restrict__ out, GaussW gw) {
    __shared__ h4 hb[4][IH][HBS4];   // {x, y, x2+y2, xy} h-blurred, fp16

    const int tid  = threadIdx.x;
    const int p    = blockIdx.z;
    const int r0   = blockIdx.y * TH - RAD;
    const int c0m8 = blockIdx.x * TW - 8;          // leftmost read col (multiple of 4)
    const float* ip = img + (size_t)p * (HH * WW);
    const float* tp = tgt + (size_t)p * (HH * WW);

    // ---- Stage AB: global -> h-blur -> hb (LDS, fp16). 4 output cols/item ----
    for (int i = tid; i < IH * 16; i += 256) {
        int r  = i >> 4;
        int cg = i & 15;
        int gr = r0 + r;
        bool rok = (gr >= 0) && (gr < HH);
        const float* xrow = ip + (size_t)gr * WW;
        const float* yrow = tp + (size_t)gr * WW;
        float fx[20], fy[20];
        #pragma unroll
        for (int t = 0; t < 5; ++t) {
            int gc = c0m8 + 4 * (cg + t);
            float4 a = make_float4(0.f, 0.f, 0.f, 0.f), b = a;
            if (rok && gc >= 0 && gc <= WW - 4) {
                a = *(const float4*)(xrow + gc);
                b = *(const float4*)(yrow + gc);
            }
            fx[4*t+0] = a.x; fx[4*t+1] = a.y; fx[4*t+2] = a.z; fx[4*t+3] = a.w;
            fy[4*t+0] = b.x; fy[4*t+1] = b.y; fy[4*t+2] = b.z; fy[4*t+3] = b.w;
        }
        float ss[14], xy[14];
        #pragma unroll
        for (int t = 0; t < 14; ++t) {
            float xv = fx[t + 3], yv = fy[t + 3];
            ss[t] = fmaf(xv, xv, yv * yv);   // x^2 + y^2
            xy[t] = xv * yv;
        }
        float a0[4] = {0,0,0,0}, a1[4] = {0,0,0,0},
              a2[4] = {0,0,0,0}, a3[4] = {0,0,0,0};
        #pragma unroll
        for (int k = 0; k < KW; ++k) {
            float g = gw.g[k];
            #pragma unroll
            for (int j = 0; j < 4; ++j) {
                a0[j] = fmaf(g, fx[3 + j + k], a0[j]);
                a1[j] = fmaf(g, fy[3 + j + k], a1[j]);
                a2[j] = fmaf(g, ss[j + k],    a2[j]);
                a3[j] = fmaf(g, xy[j + k],    a3[j]);
            }
        }
        hb[0][r][cg] = h4{(_Float16)a0[0], (_Float16)a0[1], (_Float16)a0[2], (_Float16)a0[3]};
        hb[1][r][cg] = h4{(_Float16)a1[0], (_Float16)a1[1], (_Float16)a1[2], (_Float16)a1[3]};
        hb[2][r][cg] = h4{(_Float16)a2[0], (_Float16)a2[1], (_Float16)a2[2], (_Float16)a2[3]};
        hb[3][r][cg] = h4{(_Float16)a3[0], (_Float16)a3[1], (_Float16)a3[2], (_Float16)a3[3]};
    }
    __syncthreads();

    // ---- Stage C: v-blur + SSIM; 2 rows x 4 cols per thread (all 256) ----
    const float C1 = 1e-4f;   // 0.01^2
    const float C2 = 9e-4f;   // 0.03^2
    const int cg = tid & 15;
    const int rg = tid >> 4;                 // 0..15 -> output rows 2rg, 2rg+1
    float acc[4][2][4];
    #pragma unroll
    for (int q = 0; q < 4; ++q)
        #pragma unroll
        for (int a = 0; a < 2; ++a)
            #pragma unroll
            for (int b = 0; b < 4; ++b) acc[q][a][b] = 0.f;

    #pragma unroll
    for (int kr = 0; kr < 12; ++kr) {
        int row = rg * 2 + kr;
        h4 h0 = hb[0][row][cg];
        h4 h1 = hb[1][row][cg];
        h4 h2 = hb[2][row][cg];
        h4 h3 = hb[3][row][cg];
        float v0[4], v1[4], v2[4], v3[4];
        #pragma unroll
        for (int j = 0; j < 4; ++j) {
            v0[j] = (float)h0[j]; v1[j] = (float)h1[j];
            v2[j] = (float)h2[j]; v3[j] = (float)h3[j];
        }
        #pragma unroll
        for (int ro = 0; ro < 2; ++ro) {
            int k = kr - ro;
            if (k >= 0 && k < KW) {
                float g = gw.g[k];
                #pragma unroll
                for (int j = 0; j < 4; ++j) {
                    acc[0][ro][j] = fmaf(g, v0[j], acc[0][ro][j]);
                    acc[1][ro][j] = fmaf(g, v1[j], acc[1][ro][j]);
                    acc[2][ro][j] = fmaf(g, v2[j], acc[2][ro][j]);
                    acc[3][ro][j] = fmaf(g, v3[j], acc[3][ro][j]);
                }
            }
        }
    }
    float lsum = 0.f;
    #pragma unroll
    for (int ro = 0; ro < 2; ++ro) {
        #pragma unroll
        for (int co = 0; co < 4; ++co) {
            float mu1 = acc[0][ro][co], mu2 = acc[1][ro][co];
            float mu1s = mu1 * mu1, mu2s = mu2 * mu2, mu12 = mu1 * mu2;
            float ssum = acc[2][ro][co] - mu1s - mu2s;   // s1 + s2
            float s12  = acc[3][ro][co] - mu12;
            float num = (2.f * mu12 + C1) * (2.f * s12 + C2);
            float den = (mu1s + mu2s + C1) * (ssum + C2);
            lsum = fmaf(num, __builtin_amdgcn_rcpf(den), lsum);
        }
    }

    // ---- block reduction, one atomic per block ----
    for (int off = 32; off > 0; off >>= 1)
        lsum += __shfl_down(lsum, off, 64);
    __shared__ float wsum[4];
    const int wid  = tid >> 6;
    const int lane = tid & 63;
    if (lane == 0) wsum[wid] = lsum;
    __syncthreads();
    if (tid == 0) {
        float bsum = wsum[0] + wsum[1] + wsum[2] + wsum[3];
        const float invN = 1.0f / (float)((size_t)NPLANES * HH * WW);
        atomicAdd(out, -bsum * invN);
    }
}

extern "C" void kernel_launch(void* const* d_in, const int* in_sizes, int n_in,
                              void* d_out, int out_size, void* d_ws, size_t ws_size,
                              hipStream_t stream) {
    const float* img = (const float*)d_in[0];
    const float* tgt = (const float*)d_in[1];
    float* out = (float*)d_out;

    GaussW gw;
    double g[KW], s = 0.0;
    for (int i = 0; i < KW; ++i) {
        double d = (double)(i - KW / 2);
        g[i] = exp(-(d * d) / (2.0 * 1.5 * 1.5));
        s += g[i];
    }
    for (int i = 0; i < KW; ++i) gw.g[i] = (float)(g[i] / s);

    ssim_init_out<<<1, 1, 0, stream>>>(out);

    dim3 grid(WW / TW, HH / TH, NPLANES);  // 8 x 16 x 48
    ssim_fused<<<grid, 256, 0, stream>>>(img, tgt, out, gw);
}